// Round 14
// baseline (88.288 us; speedup 1.0000x reference)
//
#include <hip/hip_runtime.h>

#define POISON 0xAAAAAAAAu
#define NMLP 16

// Exact (non-approximate) GELU, matching jax.nn.gelu(approximate=False).
__device__ __forceinline__ float gelu_exact(float x) {
    return 0.5f * x * (1.0f + erff(x * 0.7071067811865475f));
}

__device__ __forceinline__ float dot4(float4 a, float4 b) {
    return a.x * b.x + a.y * b.y + a.z * b.z + a.w * b.w;
}

// Barrier among the NMLP MLP blocks. RMW polling only (r13-verified): a
// fetch_add(0) executes at the coherence point -> always fresh, and avoids
// the acquire-load poll pathology (each acquire poll invalidates the XCD L2;
// r9/r12 crawled at 60-90 GB/s chip-wide from exactly that). Slot starts as
// harness 0xAA poison; every participant CASes POISON->0 before arriving, so
// no participant can observe POISON while polling.
__device__ __forceinline__ void mlp_barrier(unsigned* slot) {
    __syncthreads();
    if (threadIdx.x == 0) {
        atomicCAS(slot, POISON, 0u);
        __threadfence();                      // data stores drained first
        atomicAdd(slot, 1u);
        while (__hip_atomic_fetch_add(slot, 0u, __ATOMIC_ACQUIRE,
                                      __HIP_MEMORY_SCOPE_AGENT) < NMLP)
            __builtin_amdgcn_s_sleep(8);
    }
    __syncthreads();
}

// ONE dispatch, 272 blocks x 256 threads.
//   blocks 0..15   : distributed MLP (16 neurons/block/layer, 16-lane clubs,
//                    2 RMW barriers). W3/W4 row-segments are prefetched into
//                    registers BEFORE the preceding barrier so their HBM
//                    latency hides under barrier wait. L5 = per-block partial
//                    w12 merged with 12 fp32 atomicAdds, then a release
//                    fetch_add on `done`.
//   blocks 16..271 : apply. Prefetch feat float4s into registers FIRST (their
//                    ~1us HBM latency hides under the MLP), then relaxed-RMW
//                    poll `done` (no acquire-inv storm; POISON != 16 so the
//                    poison value parks the poll safely), read w12 via
//                    relaxed float fetch_add(0) (coherence-point read), FMA,
//                    store. pred[b,p,d] = sum_c feat[b,c,p] * w12[c*3+d].
__global__ __launch_bounds__(256) void fused4_kernel(
    const float* __restrict__ W1, const float* __restrict__ b1,
    const float* __restrict__ W2, const float* __restrict__ b2,
    const float* __restrict__ W3, const float* __restrict__ b3,
    const float* __restrict__ W4, const float* __restrict__ b4,
    const float* __restrict__ W5, const float* __restrict__ b5,
    const float* __restrict__ feat, float* __restrict__ out,
    float* __restrict__ ws)
{
    float*    w12  = ws;                     // bytes 0..47    (line 0)
    unsigned* done = (unsigned*)(ws + 32);   // byte  128      (line 1)
    unsigned* barA = (unsigned*)(ws + 64);   // byte  256      (line 2)
    unsigned* barB = (unsigned*)(ws + 96);   // byte  384      (line 3)
    float*    xb2  = ws + 128;               // 256 floats
    float*    xb3  = ws + 384;               // 256 floats

    __shared__ __align__(16) float xs[256];
    __shared__ float x4loc[16];
    __shared__ float wl[12];

    const int t = threadIdx.x;
    const int m = blockIdx.x;

    if (m < NMLP) {
        const int q = t >> 4;                // neuron-in-block 0..15
        const int c = t & 15;                // club lane 0..15
        const int n = m * 16 + q;            // global neuron id

        // ---- Layer 1 (redundant per block; W1 is 4KB) ----
        {
            float4 w1r = *reinterpret_cast<const float4*>(W1 + t * 4);
            xs[t] = gelu_exact(w1r.z + w1r.w + b1[t]);
        }
        __syncthreads();

        // ---- Layer 2 (+ W3 prefetch into regs before barrier A) ----
        float4 w3r[4];
        {
            float acc = 0.f;
            #pragma unroll
            for (int i = 0; i < 4; ++i) {
                float4 wv = *reinterpret_cast<const float4*>(W2 + (size_t)n * 256 + i * 64 + c * 4);
                float4 xv = *reinterpret_cast<const float4*>(xs + i * 64 + c * 4);
                acc += dot4(wv, xv);
            }
            #pragma unroll
            for (int i = 0; i < 4; ++i)
                w3r[i] = *reinterpret_cast<const float4*>(W3 + (size_t)n * 256 + i * 64 + c * 4);
            #pragma unroll
            for (int off = 1; off <= 8; off <<= 1) acc += __shfl_xor(acc, off);
            if (c == 0)
                __hip_atomic_exchange(&xb2[n], gelu_exact(acc + b2[n]),
                                      __ATOMIC_RELEASE, __HIP_MEMORY_SCOPE_AGENT);
        }
        mlp_barrier(barA);

        // ---- Layer 3 (weights already in regs; + W4 prefetch) ----
        xs[t] = xb2[t];
        __syncthreads();
        float4 w4r[4];
        {
            float acc = 0.f;
            #pragma unroll
            for (int i = 0; i < 4; ++i) {
                float4 xv = *reinterpret_cast<const float4*>(xs + i * 64 + c * 4);
                acc += dot4(w3r[i], xv);
            }
            #pragma unroll
            for (int i = 0; i < 4; ++i)
                w4r[i] = *reinterpret_cast<const float4*>(W4 + (size_t)n * 256 + i * 64 + c * 4);
            #pragma unroll
            for (int off = 1; off <= 8; off <<= 1) acc += __shfl_xor(acc, off);
            if (c == 0)
                __hip_atomic_exchange(&xb3[n], gelu_exact(acc + b3[n]),
                                      __ATOMIC_RELEASE, __HIP_MEMORY_SCOPE_AGENT);
        }
        mlp_barrier(barB);

        // ---- Layer 4 (local only) ----
        xs[t] = xb3[t];
        __syncthreads();
        {
            float acc = 0.f;
            #pragma unroll
            for (int i = 0; i < 4; ++i) {
                float4 xv = *reinterpret_cast<const float4*>(xs + i * 64 + c * 4);
                acc += dot4(w4r[i], xv);
            }
            #pragma unroll
            for (int off = 1; off <= 8; off <<= 1) acc += __shfl_xor(acc, off);
            if (c == 0) x4loc[q] = gelu_exact(acc + b4[n]);
        }
        __syncthreads();

        // ---- Layer 5 partial + done signal ----
        if (t < 12) {
            float acc = 0.f;
            #pragma unroll
            for (int qq = 0; qq < 16; ++qq)
                acc += x4loc[qq] * W5[(size_t)t * 256 + m * 16 + qq];
            if (m == 0) acc += b5[t];
            atomicCAS((unsigned*)&w12[t], POISON, 0u);   // first toucher zeroes
            atomicAdd(&w12[t], acc);
        }
        __syncthreads();                                 // adds drained
        if (t == 0) {
            atomicCAS(done, POISON, 0u);
            __hip_atomic_fetch_add(done, 1u, __ATOMIC_RELEASE,
                                   __HIP_MEMORY_SCOPE_AGENT);
        }
        return;
    }

    // ================= apply blocks =================
    const int a   = m - NMLP;                  // 0..255
    const int idx = a * 256 + t;               // 0..65535 quad index
    const int b   = idx >> 14;                 // batch
    const int pos = (idx & 16383) << 2;        // pixel start (x4)

    // Prefetch feat into registers BEFORE waiting (latency hides under MLP).
    const float* fb = feat + (size_t)b * 4 * 65536 + pos;
    const float4 f0 = *reinterpret_cast<const float4*>(fb);
    const float4 f1 = *reinterpret_cast<const float4*>(fb + 65536);
    const float4 f2 = *reinterpret_cast<const float4*>(fb + 131072);
    const float4 f3 = *reinterpret_cast<const float4*>(fb + 196608);

    // Relaxed RMW poll: coherence-point read, no cache invalidation.
    // POISON (0xAAAAAAAA) != 16, partial counts < 16 -> only full 16 exits.
    if (t == 0) {
        while (__hip_atomic_fetch_add(done, 0u, __ATOMIC_RELAXED,
                                      __HIP_MEMORY_SCOPE_AGENT) != (unsigned)NMLP)
            __builtin_amdgcn_s_sleep(16);
    }
    __syncthreads();
    if (t < 12)
        wl[t] = __hip_atomic_fetch_add(&w12[t], 0.0f, __ATOMIC_RELAXED,
                                       __HIP_MEMORY_SCOPE_AGENT);
    __syncthreads();

    float wr[12];
    #pragma unroll
    for (int i = 0; i < 12; ++i) wr[i] = wl[i];

    float r[12];
    #pragma unroll
    for (int dd = 0; dd < 3; ++dd) {
        r[0 + dd] = f0.x * wr[dd] + f1.x * wr[3 + dd] + f2.x * wr[6 + dd] + f3.x * wr[9 + dd];
        r[3 + dd] = f0.y * wr[dd] + f1.y * wr[3 + dd] + f2.y * wr[6 + dd] + f3.y * wr[9 + dd];
        r[6 + dd] = f0.z * wr[dd] + f1.z * wr[3 + dd] + f2.z * wr[6 + dd] + f3.z * wr[9 + dd];
        r[9 + dd] = f0.w * wr[dd] + f1.w * wr[3 + dd] + f2.w * wr[6 + dd] + f3.w * wr[9 + dd];
    }

    float* op = out + (size_t)(b * 65536 + pos) * 3;
    reinterpret_cast<float4*>(op)[0] = make_float4(r[0], r[1], r[2],  r[3]);
    reinterpret_cast<float4*>(op)[1] = make_float4(r[4], r[5], r[6],  r[7]);
    reinterpret_cast<float4*>(op)[2] = make_float4(r[8], r[9], r[10], r[11]);
}

extern "C" void kernel_launch(void* const* d_in, const int* in_sizes, int n_in,
                              void* d_out, int out_size, void* d_ws, size_t ws_size,
                              hipStream_t stream) {
    const float* feat = (const float*)d_in[0];
    const float* W1   = (const float*)d_in[1];
    const float* b1   = (const float*)d_in[2];
    const float* W2   = (const float*)d_in[3];
    const float* b2   = (const float*)d_in[4];
    const float* W3   = (const float*)d_in[5];
    const float* b3   = (const float*)d_in[6];
    const float* W4   = (const float*)d_in[7];
    const float* b4   = (const float*)d_in[8];
    const float* W5   = (const float*)d_in[9];
    const float* b5   = (const float*)d_in[10];

    float* out = (float*)d_out;   // [4, 65536, 3] fp32
    float* ws  = (float*)d_ws;

    fused4_kernel<<<NMLP + 256, 256, 0, stream>>>(W1, b1, W2, b2, W3, b3,
                                                  W4, b4, W5, b5, feat, out, ws);
}

// Round 15
// 84.967 us; speedup vs baseline: 1.0391x; 1.0391x over previous
//
#include <hip/hip_runtime.h>

#define POISON 0xAAAAAAAAu
#define NMLP 16u

// Exact (non-approximate) GELU, matching jax.nn.gelu(approximate=False).
__device__ __forceinline__ float gelu_exact(float x) {
    return 0.5f * x * (1.0f + erff(x * 0.7071067811865475f));
}

__device__ __forceinline__ float dot4(float4 a, float4 b) {
    return a.x * b.x + a.y * b.y + a.z * b.z + a.w * b.w;
}

// Barrier among NMLP=16 blocks. RMW polling only (r13-verified): fetch_add(0)
// executes at the coherence point -> always fresh, no cache-invalidate
// broadcast (the acquire-LOAD spin of r9/r12 invalidated L2 per poll and
// crawled the chip at 60-90 GB/s). 16 pollers at ~256cy interval on one line
// is negligible. Slot starts as harness 0xAA poison; every participant CASes
// POISON->0 before arriving, so no participant can observe POISON in a poll.
__device__ __forceinline__ void mlp_barrier(unsigned* slot) {
    __syncthreads();
    if (threadIdx.x == 0) {
        atomicCAS(slot, POISON, 0u);
        __threadfence();                      // data stores drained first
        atomicAdd(slot, 1u);
        while (__hip_atomic_fetch_add(slot, 0u, __ATOMIC_ACQUIRE,
                                      __HIP_MEMORY_SCOPE_AGENT) < NMLP)
            __builtin_amdgcn_s_sleep(4);
    }
    __syncthreads();
}

// K1: whole MLP on 16 blocks x 256 threads (r13 structure + W3/W4 register
// prefetch from fused4: each next layer's 4 float4 row-segments are issued
// BEFORE the preceding barrier so their HBM/L2 latency hides under barrier
// arrival spread instead of serializing after it).
//  Layer layout (256x256): block m owns neurons m*16..m*16+15; 16 threads
//  per neuron (club c reads 256B contiguous per i-step), 4-step shfl reduce.
//  L5 linear => per-block partial w12 merged with 12 fp32 atomicAdds; the
//  K1->K2 kernel boundary is the final sync (cheapest 256-way sync, r14).
__global__ __launch_bounds__(256) void mlp16_kernel(
    const float* __restrict__ W1, const float* __restrict__ b1,
    const float* __restrict__ W2, const float* __restrict__ b2,
    const float* __restrict__ W3, const float* __restrict__ b3,
    const float* __restrict__ W4, const float* __restrict__ b4,
    const float* __restrict__ W5, const float* __restrict__ b5,
    float* __restrict__ ws)
{
    float*    w12  = ws;                     // 12 partial-sum accumulators
    unsigned* barA = (unsigned*)(ws + 32);
    unsigned* barB = (unsigned*)(ws + 64);
    float*    xb2  = ws + 128;               // 256 floats
    float*    xb3  = ws + 384;               // 256 floats

    __shared__ __align__(16) float xs[256];
    __shared__ float x4loc[16];

    const int t = threadIdx.x;
    const int m = blockIdx.x;                // 0..15
    const int q = t >> 4;                    // neuron-in-block 0..15
    const int c = t & 15;                    // club lane 0..15
    const int n = m * 16 + q;                // global neuron id

    // ---- Layer 1 (redundant per block; W1 is 4KB) ----
    {
        float4 w1r = *reinterpret_cast<const float4*>(W1 + t * 4);
        xs[t] = gelu_exact(w1r.z + w1r.w + b1[t]);
    }
    __syncthreads();

    // ---- Layer 2 (+ W3 prefetch into regs before barrier A) ----
    float4 w3r[4];
    {
        float acc = 0.f;
        #pragma unroll
        for (int i = 0; i < 4; ++i) {
            float4 wv = *reinterpret_cast<const float4*>(W2 + (size_t)n * 256 + i * 64 + c * 4);
            float4 xv = *reinterpret_cast<const float4*>(xs + i * 64 + c * 4);
            acc += dot4(wv, xv);
        }
        #pragma unroll
        for (int i = 0; i < 4; ++i)
            w3r[i] = *reinterpret_cast<const float4*>(W3 + (size_t)n * 256 + i * 64 + c * 4);
        #pragma unroll
        for (int off = 1; off <= 8; off <<= 1) acc += __shfl_xor(acc, off);
        if (c == 0)
            __hip_atomic_exchange(&xb2[n], gelu_exact(acc + b2[n]),
                                  __ATOMIC_RELEASE, __HIP_MEMORY_SCOPE_AGENT);
    }
    mlp_barrier(barA);

    // ---- Layer 3 (weights already in regs; + W4 prefetch before barrier B) ----
    xs[t] = xb2[t];                          // fresh: post-RMW-acquire
    __syncthreads();
    float4 w4r[4];
    {
        float acc = 0.f;
        #pragma unroll
        for (int i = 0; i < 4; ++i) {
            float4 xv = *reinterpret_cast<const float4*>(xs + i * 64 + c * 4);
            acc += dot4(w3r[i], xv);
        }
        #pragma unroll
        for (int i = 0; i < 4; ++i)
            w4r[i] = *reinterpret_cast<const float4*>(W4 + (size_t)n * 256 + i * 64 + c * 4);
        #pragma unroll
        for (int off = 1; off <= 8; off <<= 1) acc += __shfl_xor(acc, off);
        if (c == 0)
            __hip_atomic_exchange(&xb3[n], gelu_exact(acc + b3[n]),
                                  __ATOMIC_RELEASE, __HIP_MEMORY_SCOPE_AGENT);
    }
    mlp_barrier(barB);

    // ---- Layer 4 (weights in regs; only this block's 16 outputs needed) ----
    xs[t] = xb3[t];
    __syncthreads();
    {
        float acc = 0.f;
        #pragma unroll
        for (int i = 0; i < 4; ++i) {
            float4 xv = *reinterpret_cast<const float4*>(xs + i * 64 + c * 4);
            acc += dot4(w4r[i], xv);
        }
        #pragma unroll
        for (int off = 1; off <= 8; off <<= 1) acc += __shfl_xor(acc, off);
        if (c == 0) x4loc[q] = gelu_exact(acc + b4[n]);
    }
    __syncthreads();

    // ---- Layer 5 partial: w12_m[j] = sum_qq W5[j, m*16+qq] * x4loc[qq] ----
    if (t < 12) {
        float acc = 0.f;
        #pragma unroll
        for (int qq = 0; qq < 16; ++qq)
            acc += x4loc[qq] * W5[(size_t)t * 256 + m * 16 + qq];
        if (m == 0) acc += b5[t];
        atomicCAS((unsigned*)&w12[t], POISON, 0u);  // first toucher zeroes
        atomicAdd(&w12[t], acc);                    // visible to K2 via boundary
    }
}

// K2: pred[b,p,d] = sum_c feat[b,c,p] * w12[c*3+d].
// feat: [B=4, C=4, HW=65536] fp32, out: [B, HW, 3] fp32. 256 blk x 256 thr.
__global__ __launch_bounds__(256) void apply_kernel(
    const float* __restrict__ feat, const float* __restrict__ w12,
    float* __restrict__ out)
{
    __shared__ float wl[12];
    const int t = threadIdx.x;
    if (t < 12) wl[t] = w12[t];
    __syncthreads();

    float wr[12];
    #pragma unroll
    for (int i = 0; i < 12; ++i) wr[i] = wl[i];

    const int idx = blockIdx.x * 256 + t;            // 0..65535
    const int b   = idx >> 14;                        // batch
    const int pos = (idx & 16383) << 2;               // pixel start (x4)

    const float* fb = feat + (size_t)b * 4 * 65536 + pos;
    const float4 f0 = *reinterpret_cast<const float4*>(fb);
    const float4 f1 = *reinterpret_cast<const float4*>(fb + 65536);
    const float4 f2 = *reinterpret_cast<const float4*>(fb + 131072);
    const float4 f3 = *reinterpret_cast<const float4*>(fb + 196608);

    float r[12];
    #pragma unroll
    for (int dd = 0; dd < 3; ++dd) {
        r[0 + dd] = f0.x * wr[dd] + f1.x * wr[3 + dd] + f2.x * wr[6 + dd] + f3.x * wr[9 + dd];
        r[3 + dd] = f0.y * wr[dd] + f1.y * wr[3 + dd] + f2.y * wr[6 + dd] + f3.y * wr[9 + dd];
        r[6 + dd] = f0.z * wr[dd] + f1.z * wr[3 + dd] + f2.z * wr[6 + dd] + f3.z * wr[9 + dd];
        r[9 + dd] = f0.w * wr[dd] + f1.w * wr[3 + dd] + f2.w * wr[6 + dd] + f3.w * wr[9 + dd];
    }

    float* op = out + (size_t)(b * 65536 + pos) * 3;
    reinterpret_cast<float4*>(op)[0] = make_float4(r[0], r[1], r[2],  r[3]);
    reinterpret_cast<float4*>(op)[1] = make_float4(r[4], r[5], r[6],  r[7]);
    reinterpret_cast<float4*>(op)[2] = make_float4(r[8], r[9], r[10], r[11]);
}

extern "C" void kernel_launch(void* const* d_in, const int* in_sizes, int n_in,
                              void* d_out, int out_size, void* d_ws, size_t ws_size,
                              hipStream_t stream) {
    const float* feat = (const float*)d_in[0];
    const float* W1   = (const float*)d_in[1];
    const float* b1   = (const float*)d_in[2];
    const float* W2   = (const float*)d_in[3];
    const float* b2   = (const float*)d_in[4];
    const float* W3   = (const float*)d_in[5];
    const float* b3   = (const float*)d_in[6];
    const float* W4   = (const float*)d_in[7];
    const float* b4   = (const float*)d_in[8];
    const float* W5   = (const float*)d_in[9];
    const float* b5   = (const float*)d_in[10];

    float* out = (float*)d_out;   // [4, 65536, 3] fp32
    float* ws  = (float*)d_ws;

    mlp16_kernel<<<NMLP, 256, 0, stream>>>(W1, b1, W2, b2, W3, b3, W4, b4,
                                           W5, b5, ws);
    apply_kernel<<<256, 256, 0, stream>>>(feat, ws, out);
}

// Round 16
// 83.601 us; speedup vs baseline: 1.0561x; 1.0163x over previous
//
#include <hip/hip_runtime.h>

#define POISON 0xAAAAAAAAu
#define NMLP 16u

// Exact (non-approximate) GELU, matching jax.nn.gelu(approximate=False).
__device__ __forceinline__ float gelu_exact(float x) {
    return 0.5f * x * (1.0f + erff(x * 0.7071067811865475f));
}

__device__ __forceinline__ float dot4(float4 a, float4 b) {
    return a.x * b.x + a.y * b.y + a.z * b.z + a.w * b.w;
}

// 16-block barrier, RELAXED polling (r15 lesson): an ACQUIRE RMW poll emits a
// cache-invalidate per poll (r9/r12's chip-crawl mechanism; r15's sleep(4)
// acquire polls still cost ~4.5us/barrier by continuously invalidating the
// polling XCD's caches mid-layer). Relaxed fetch_add(0) reads the coherence
// point with NO invalidate; ONE __threadfence() after exit performs the
// single invalidate needed so post-barrier plain loads of xb* are fresh.
// Arrival needs no pre-fence: the xb stores are coherence-point atomic
// exchanges already drained by __syncthreads' vmcnt wait.
// Slots are CAS-initialized from harness 0xAA poison at kernel entry (every
// block CASes before any arrival add can touch the line).
__device__ __forceinline__ void mlp_barrier(unsigned* slot) {
    __syncthreads();
    if (threadIdx.x == 0) {
        atomicAdd(slot, 1u);
        while (__hip_atomic_fetch_add(slot, 0u, __ATOMIC_RELAXED,
                                      __HIP_MEMORY_SCOPE_AGENT) < NMLP)
            __builtin_amdgcn_s_sleep(16);
        __threadfence();               // single acquire-invalidate
    }
    __syncthreads();
}

// K1: whole MLP on 16 blocks x 256 threads (r13 structure; only the barrier
// poll semantics changed).
//  Layer layout (256x256): block m owns neurons m*16..m*16+15; 16 threads
//  per neuron (club c reads 256B contiguous per i-step), 4-step shfl reduce.
//  L5 linear => per-block partial w12 merged with 12 fp32 atomicAdds; the
//  K1->K2 kernel boundary is the final sync (cheapest 256-way sync, r14).
__global__ __launch_bounds__(256) void mlp16_kernel(
    const float* __restrict__ W1, const float* __restrict__ b1,
    const float* __restrict__ W2, const float* __restrict__ b2,
    const float* __restrict__ W3, const float* __restrict__ b3,
    const float* __restrict__ W4, const float* __restrict__ b4,
    const float* __restrict__ W5, const float* __restrict__ b5,
    float* __restrict__ ws)
{
    float*    w12  = ws;                     // 12 partial-sum accumulators
    unsigned* barA = (unsigned*)(ws + 32);
    unsigned* barB = (unsigned*)(ws + 64);
    float*    xb2  = ws + 128;               // 256 floats
    float*    xb3  = ws + 384;               // 256 floats

    __shared__ __align__(16) float xs[256];
    __shared__ float x4loc[16];

    const int t = threadIdx.x;
    const int m = blockIdx.x;                // 0..15
    const int q = t >> 4;                    // neuron-in-block 0..15
    const int c = t & 15;                    // club lane 0..15
    const int n = m * 16 + q;                // global neuron id

    // Hoisted barrier-slot init: all blocks CAS poison->0 before any arrival.
    if (t == 0) {
        atomicCAS(barA, POISON, 0u);
        atomicCAS(barB, POISON, 0u);
    }

    // ---- Layer 1 (redundant per block; W1 is 4KB) ----
    {
        float4 w1r = *reinterpret_cast<const float4*>(W1 + t * 4);
        xs[t] = gelu_exact(w1r.z + w1r.w + b1[t]);
    }
    __syncthreads();

    // ---- Layer 2 ----
    {
        float acc = 0.f;
        #pragma unroll
        for (int i = 0; i < 4; ++i) {
            float4 wv = *reinterpret_cast<const float4*>(W2 + (size_t)n * 256 + i * 64 + c * 4);
            float4 xv = *reinterpret_cast<const float4*>(xs + i * 64 + c * 4);
            acc += dot4(wv, xv);
        }
        #pragma unroll
        for (int off = 1; off <= 8; off <<= 1) acc += __shfl_xor(acc, off);
        if (c == 0)
            __hip_atomic_exchange(&xb2[n], gelu_exact(acc + b2[n]),
                                  __ATOMIC_RELEASE, __HIP_MEMORY_SCOPE_AGENT);
    }
    mlp_barrier(barA);

    // ---- Layer 3 ----
    xs[t] = xb2[t];                          // fresh: post-fence invalidate
    __syncthreads();
    {
        float acc = 0.f;
        #pragma unroll
        for (int i = 0; i < 4; ++i) {
            float4 wv = *reinterpret_cast<const float4*>(W3 + (size_t)n * 256 + i * 64 + c * 4);
            float4 xv = *reinterpret_cast<const float4*>(xs + i * 64 + c * 4);
            acc += dot4(wv, xv);
        }
        #pragma unroll
        for (int off = 1; off <= 8; off <<= 1) acc += __shfl_xor(acc, off);
        if (c == 0)
            __hip_atomic_exchange(&xb3[n], gelu_exact(acc + b3[n]),
                                  __ATOMIC_RELEASE, __HIP_MEMORY_SCOPE_AGENT);
    }
    mlp_barrier(barB);

    // ---- Layer 4 (only this block's 16 outputs needed locally) ----
    xs[t] = xb3[t];
    __syncthreads();
    {
        float acc = 0.f;
        #pragma unroll
        for (int i = 0; i < 4; ++i) {
            float4 wv = *reinterpret_cast<const float4*>(W4 + (size_t)n * 256 + i * 64 + c * 4);
            float4 xv = *reinterpret_cast<const float4*>(xs + i * 64 + c * 4);
            acc += dot4(wv, xv);
        }
        #pragma unroll
        for (int off = 1; off <= 8; off <<= 1) acc += __shfl_xor(acc, off);
        if (c == 0) x4loc[q] = gelu_exact(acc + b4[n]);
    }
    __syncthreads();

    // ---- Layer 5 partial: w12_m[j] = sum_qq W5[j, m*16+qq] * x4loc[qq] ----
    if (t < 12) {
        float acc = 0.f;
        #pragma unroll
        for (int qq = 0; qq < 16; ++qq)
            acc += x4loc[qq] * W5[(size_t)t * 256 + m * 16 + qq];
        if (m == 0) acc += b5[t];
        atomicCAS((unsigned*)&w12[t], POISON, 0u);  // first toucher zeroes
        atomicAdd(&w12[t], acc);                    // visible to K2 via boundary
    }
}

// K2: pred[b,p,d] = sum_c feat[b,c,p] * w12[c*3+d].
// feat: [B=4, C=4, HW=65536] fp32, out: [B, HW, 3] fp32. 256 blk x 256 thr.
__global__ __launch_bounds__(256) void apply_kernel(
    const float* __restrict__ feat, const float* __restrict__ w12,
    float* __restrict__ out)
{
    __shared__ float wl[12];
    const int t = threadIdx.x;
    if (t < 12) wl[t] = w12[t];
    __syncthreads();

    float wr[12];
    #pragma unroll
    for (int i = 0; i < 12; ++i) wr[i] = wl[i];

    const int idx = blockIdx.x * 256 + t;            // 0..65535
    const int b   = idx >> 14;                        // batch
    const int pos = (idx & 16383) << 2;               // pixel start (x4)

    const float* fb = feat + (size_t)b * 4 * 65536 + pos;
    const float4 f0 = *reinterpret_cast<const float4*>(fb);
    const float4 f1 = *reinterpret_cast<const float4*>(fb + 65536);
    const float4 f2 = *reinterpret_cast<const float4*>(fb + 131072);
    const float4 f3 = *reinterpret_cast<const float4*>(fb + 196608);

    float r[12];
    #pragma unroll
    for (int dd = 0; dd < 3; ++dd) {
        r[0 + dd] = f0.x * wr[dd] + f1.x * wr[3 + dd] + f2.x * wr[6 + dd] + f3.x * wr[9 + dd];
        r[3 + dd] = f0.y * wr[dd] + f1.y * wr[3 + dd] + f2.y * wr[6 + dd] + f3.y * wr[9 + dd];
        r[6 + dd] = f0.z * wr[dd] + f1.z * wr[3 + dd] + f2.z * wr[6 + dd] + f3.z * wr[9 + dd];
        r[9 + dd] = f0.w * wr[dd] + f1.w * wr[3 + dd] + f2.w * wr[6 + dd] + f3.w * wr[9 + dd];
    }

    float* op = out + (size_t)(b * 65536 + pos) * 3;
    reinterpret_cast<float4*>(op)[0] = make_float4(r[0], r[1], r[2],  r[3]);
    reinterpret_cast<float4*>(op)[1] = make_float4(r[4], r[5], r[6],  r[7]);
    reinterpret_cast<float4*>(op)[2] = make_float4(r[8], r[9], r[10], r[11]);
}

extern "C" void kernel_launch(void* const* d_in, const int* in_sizes, int n_in,
                              void* d_out, int out_size, void* d_ws, size_t ws_size,
                              hipStream_t stream) {
    const float* feat = (const float*)d_in[0];
    const float* W1   = (const float*)d_in[1];
    const float* b1   = (const float*)d_in[2];
    const float* W2   = (const float*)d_in[3];
    const float* b2   = (const float*)d_in[4];
    const float* W3   = (const float*)d_in[5];
    const float* b3   = (const float*)d_in[6];
    const float* W4   = (const float*)d_in[7];
    const float* b4   = (const float*)d_in[8];
    const float* W5   = (const float*)d_in[9];
    const float* b5   = (const float*)d_in[10];

    float* out = (float*)d_out;   // [4, 65536, 3] fp32
    float* ws  = (float*)d_ws;

    mlp16_kernel<<<NMLP, 256, 0, stream>>>(W1, b1, W2, b2, W3, b3, W4, b4,
                                           W5, b5, ws);
    apply_kernel<<<256, 256, 0, stream>>>(feat, ws, out);
}

// Round 17
// 82.158 us; speedup vs baseline: 1.0746x; 1.0176x over previous
//
#include <hip/hip_runtime.h>

// Exact (non-approximate) GELU, matching jax.nn.gelu(approximate=False).
__device__ __forceinline__ float gelu_exact(float x) {
    return 0.5f * x * (1.0f + erff(x * 0.7071067811865475f));
}

__device__ __forceinline__ float dot4(float4 a, float4 b) {
    return a.x * b.x + a.y * b.y + a.z * b.z + a.w * b.w;
}

// K-split MLP, NO barriers, NO atomics (r16 lesson: every sync flavor costs
// ~3-4us; the old structure had 3 syncs + atomic merges). Block m owns
// k-slice [m*16, m*16+16): it computes its own x-slice, then PARTIAL
// pre-activations for ALL 256 next-layer neurons over its slice, stored to
// z*p[m][0..255] with plain coalesced stores. The next kernel sums the 16
// partial vectors in fixed j-order (deterministic, bit-stable). Cross-kernel
// plain store->load visibility via dispatch-boundary cache maintenance is
// r7-validated (its per-layer chain passed with exactly this pattern).
//
// ws layout (floats): z3p = ws[0..4095]  (16 x 256)
//                     z4p = ws[4096..8191]
// Both are fully overwritten before being read -> no poison init needed.

// K1 (16 blocks x 256): x1 (redundant, 4KB) -> x2 slice -> z3 partials.
__global__ __launch_bounds__(256) void k1_kernel(
    const float* __restrict__ W1, const float* __restrict__ b1,
    const float* __restrict__ W2, const float* __restrict__ b2,
    const float* __restrict__ W3, float* __restrict__ ws)
{
    float* z3p = ws;                         // [16][256]
    __shared__ __align__(16) float x1l[256];
    __shared__ __align__(16) float x2l[16];

    const int t = threadIdx.x;
    const int m = blockIdx.x;                // k-slice 0..15
    const int q = t >> 4;                    // neuron-in-slice 0..15
    const int c = t & 15;                    // club lane 0..15

    // Layer 1: MLP input is [0,0,1,1]; W1 [256,4] row-major.
    {
        float4 w1r = *reinterpret_cast<const float4*>(W1 + t * 4);
        x1l[t] = gelu_exact(w1r.z + w1r.w + b1[t]);
    }
    __syncthreads();

    // Layer 2, this block's 16 neurons: n = m*16+q; club c covers 16 elems.
    {
        const int n = m * 16 + q;
        float acc = 0.f;
        #pragma unroll
        for (int i = 0; i < 4; ++i) {
            float4 wv = *reinterpret_cast<const float4*>(W2 + (size_t)n * 256 + c * 16 + i * 4);
            float4 xv = *reinterpret_cast<const float4*>(x1l + c * 16 + i * 4);
            acc += dot4(wv, xv);
        }
        #pragma unroll
        for (int off = 1; off <= 8; off <<= 1) acc += __shfl_xor(acc, off);
        if (c == 0) x2l[q] = gelu_exact(acc + b2[n]);
    }
    __syncthreads();

    // L3 partials: thread t -> neuron t, over k in [m*16, m*16+16).
    {
        float a3 = 0.f;
        #pragma unroll
        for (int i = 0; i < 4; ++i) {
            float4 wv = *reinterpret_cast<const float4*>(W3 + (size_t)t * 256 + m * 16 + i * 4);
            float4 xv = *reinterpret_cast<const float4*>(x2l + i * 4);
            a3 += dot4(wv, xv);
        }
        z3p[m * 256 + t] = a3;               // coalesced 1KB store
    }
}

// K2 (16 blocks x 256): merge z3 slice -> x3 slice -> z4 partials.
__global__ __launch_bounds__(256) void k2_kernel(
    const float* __restrict__ b3, const float* __restrict__ W4,
    float* __restrict__ ws)
{
    const float* z3p = ws;
    float*       z4p = ws + 4096;
    __shared__ float zred[256];
    __shared__ __align__(16) float x3l[16];

    const int t = threadIdx.x;
    const int m = blockIdx.x;                // k-slice 0..15
    const int j = t >> 4;                    // partial index 0..15
    const int i = t & 15;                    // neuron-in-slice 0..15

    // Gather the 16 partials of this block's 16 z3 values (1KB total).
    zred[t] = z3p[j * 256 + m * 16 + i];
    __syncthreads();
    if (t < 16) {
        float s = 0.f;
        #pragma unroll
        for (int jj = 0; jj < 16; ++jj) s += zred[jj * 16 + t];   // fixed order
        x3l[t] = gelu_exact(s + b3[m * 16 + t]);
    }
    __syncthreads();

    // L4 partials: thread t -> neuron t, over k in [m*16, m*16+16).
    {
        float a4 = 0.f;
        #pragma unroll
        for (int ii = 0; ii < 4; ++ii) {
            float4 wv = *reinterpret_cast<const float4*>(W4 + (size_t)t * 256 + m * 16 + ii * 4);
            float4 xv = *reinterpret_cast<const float4*>(x3l + ii * 4);
            a4 += dot4(wv, xv);
        }
        z4p[m * 256 + t] = a4;
    }
}

// K3 (256 blocks x 256): merge z4 -> x4 -> w12 (redundant, 12KB W5) -> apply.
// pred[b,p,d] = sum_c feat[b,c,p] * w12[c*3+d].
__global__ __launch_bounds__(256) void k3_kernel(
    const float* __restrict__ b4, const float* __restrict__ W5,
    const float* __restrict__ b5, const float* __restrict__ feat,
    float* __restrict__ out, const float* __restrict__ ws)
{
    const float* z4p = ws + 4096;
    __shared__ __align__(16) float x4l[256];
    __shared__ float wl[12];

    const int t = threadIdx.x;

    // Apply-slice addresses; issue feat loads FIRST (latency overlaps merge).
    const int idx = blockIdx.x * 256 + t;    // 0..65535 quad index
    const int b   = idx >> 14;
    const int pos = (idx & 16383) << 2;
    const float* fb = feat + (size_t)b * 4 * 65536 + pos;
    const float4 f0 = *reinterpret_cast<const float4*>(fb);
    const float4 f1 = *reinterpret_cast<const float4*>(fb + 65536);
    const float4 f2 = *reinterpret_cast<const float4*>(fb + 131072);
    const float4 f3 = *reinterpret_cast<const float4*>(fb + 196608);

    // Merge z4 (fixed order) + gelu -> x4.
    {
        float s = b4[t];
        #pragma unroll
        for (int j = 0; j < 16; ++j) s += z4p[j * 256 + t];  // coalesced per j
        x4l[t] = gelu_exact(s);
    }
    __syncthreads();

    // w12 = W5 @ x4 + b5 (12 outputs; club of 16 per output, shfl reduce).
    {
        const int q = t >> 4;                // 0..15 (12 used)
        const int c = t & 15;
        if (q < 12) {
            float acc = 0.f;
            #pragma unroll
            for (int i = 0; i < 4; ++i) {
                float4 wv = *reinterpret_cast<const float4*>(W5 + (size_t)q * 256 + c * 16 + i * 4);
                float4 xv = *reinterpret_cast<const float4*>(x4l + c * 16 + i * 4);
                acc += dot4(wv, xv);
            }
            #pragma unroll
            for (int off = 1; off <= 8; off <<= 1) acc += __shfl_xor(acc, off);
            if (c == 0) wl[q] = acc + b5[q];
        }
    }
    __syncthreads();

    float wr[12];
    #pragma unroll
    for (int i = 0; i < 12; ++i) wr[i] = wl[i];

    float r[12];
    #pragma unroll
    for (int dd = 0; dd < 3; ++dd) {
        r[0 + dd] = f0.x * wr[dd] + f1.x * wr[3 + dd] + f2.x * wr[6 + dd] + f3.x * wr[9 + dd];
        r[3 + dd] = f0.y * wr[dd] + f1.y * wr[3 + dd] + f2.y * wr[6 + dd] + f3.y * wr[9 + dd];
        r[6 + dd] = f0.z * wr[dd] + f1.z * wr[3 + dd] + f2.z * wr[6 + dd] + f3.z * wr[9 + dd];
        r[9 + dd] = f0.w * wr[dd] + f1.w * wr[3 + dd] + f2.w * wr[6 + dd] + f3.w * wr[9 + dd];
    }

    float* op = out + (size_t)(b * 65536 + pos) * 3;
    reinterpret_cast<float4*>(op)[0] = make_float4(r[0], r[1], r[2],  r[3]);
    reinterpret_cast<float4*>(op)[1] = make_float4(r[4], r[5], r[6],  r[7]);
    reinterpret_cast<float4*>(op)[2] = make_float4(r[8], r[9], r[10], r[11]);
}

extern "C" void kernel_launch(void* const* d_in, const int* in_sizes, int n_in,
                              void* d_out, int out_size, void* d_ws, size_t ws_size,
                              hipStream_t stream) {
    const float* feat = (const float*)d_in[0];
    const float* W1   = (const float*)d_in[1];
    const float* b1   = (const float*)d_in[2];
    const float* W2   = (const float*)d_in[3];
    const float* b2   = (const float*)d_in[4];
    const float* W3   = (const float*)d_in[5];
    const float* b3   = (const float*)d_in[6];
    const float* W4   = (const float*)d_in[7];
    const float* b4   = (const float*)d_in[8];
    const float* W5   = (const float*)d_in[9];
    const float* b5   = (const float*)d_in[10];

    float* out = (float*)d_out;   // [4, 65536, 3] fp32
    float* ws  = (float*)d_ws;

    k1_kernel<<<16, 256, 0, stream>>>(W1, b1, W2, b2, W3, ws);
    k2_kernel<<<16, 256, 0, stream>>>(b3, W4, ws);
    k3_kernel<<<256, 256, 0, stream>>>(b4, W5, b5, feat, out, ws);
}